// Round 1
// baseline (234.020 us; speedup 1.0000x reference)
//
#include <hip/hip_runtime.h>

#define BATCH 8
#define TLEN  2048
#define CDIM  768

// ---------------------------------------------------------------------------
// Phase 1: for each (b,i) find best_j = argmax_j<i  f32(L[i,j]) + f32(j)*1e-5f
// (first-occurrence-of-max, float32 semantics), where L = longest suffix match
// run length.  Lazy evaluation: only j with x[j]==x[i] can have L>=1, and only
// those can win (any L>=1 beats every L==0 score).  If no match -> pred = -1,
// else pred = x[best_j + 1].
//
// Block: 256 threads = 64 positions x 4 j-range parts. Token row in LDS (8KB).
// ---------------------------------------------------------------------------
__global__ __launch_bounds__(256) void rosa_pred_kernel(const int* __restrict__ idx,
                                                        int* __restrict__ pred) {
    __shared__ int xs[TLEN];
    const int b   = blockIdx.x;
    const int i0  = blockIdx.y * 64;
    const int tid = threadIdx.x;

    const int* __restrict__ xrow = idx + b * TLEN;
    for (int t = tid; t < TLEN; t += 256) xs[t] = xrow[t];
    __syncthreads();

    const int i    = i0 + (tid >> 2);
    const int part = tid & 3;
    const int xi   = xs[i];

    // split j in [0, i) into 4 contiguous chunks (contiguity preserves the
    // "smaller j wins ties" combine rule)
    const int chunk = (i + 3) >> 2;
    const int jlo   = part * chunk;
    const int jhi   = min(jlo + chunk, i);

    float bestS = -1.0f;
    int   bestJ = 0;

    for (int j = jlo; j < jhi; ++j) {
        if (xs[j] == xi) {
            // walk back along the diagonal; DP floor is column 0 (m <= j)
            int L = 1;
            int m = 1;
            while (m <= j && xs[i - m] == xs[j - m]) { ++L; ++m; }
            // EXACT float32 scoring as in the reference: round(j*1e-5) then add.
            const float s = __fadd_rn((float)L, __fmul_rn((float)j, 1e-5f));
            if (s > bestS) { bestS = s; bestJ = j; }   // strict > == first max
        }
    }

    // combine the 4 parts (adjacent lanes): bigger s wins, tie -> smaller j
    #pragma unroll
    for (int off = 1; off < 4; off <<= 1) {
        const float oS = __shfl_xor(bestS, off, 64);
        const int   oJ = __shfl_xor(bestJ, off, 64);
        if (oS > bestS || (oS == bestS && oJ < bestJ)) { bestS = oS; bestJ = oJ; }
    }

    if (part == 0) {
        int p = -1;
        if (bestS >= 0.5f) {                 // some L >= 1 existed
            const int pi = min(bestJ + 1, TLEN - 1);
            p = xs[pi];
        }
        pred[b * TLEN + i] = p;
    }
}

// ---------------------------------------------------------------------------
// Phase 2: out[b,i,:] = (pred<0) ? 0 : emb[pred,:].  One wave per row,
// 3 x float4 per lane (64*3*4 = 768 floats).
// ---------------------------------------------------------------------------
__global__ __launch_bounds__(256) void rosa_gather_kernel(const int* __restrict__ pred,
                                                          const float* __restrict__ emb,
                                                          float* __restrict__ out) {
    const int row  = blockIdx.x * 4 + (threadIdx.x >> 6);
    const int lane = threadIdx.x & 63;
    const int p    = pred[row];

    float4* __restrict__ o = (float4*)(out + (size_t)row * CDIM);
    if (p < 0) {
        const float4 z = make_float4(0.f, 0.f, 0.f, 0.f);
        #pragma unroll
        for (int k = 0; k < 3; ++k) o[lane + k * 64] = z;
    } else {
        const float4* __restrict__ e = (const float4*)(emb + (size_t)p * CDIM);
        #pragma unroll
        for (int k = 0; k < 3; ++k) o[lane + k * 64] = e[lane + k * 64];
    }
}

extern "C" void kernel_launch(void* const* d_in, const int* in_sizes, int n_in,
                              void* d_out, int out_size, void* d_ws, size_t ws_size,
                              hipStream_t stream) {
    const int*   idx = (const int*)d_in[0];     // (B,T) int32
    const float* emb = (const float*)d_in[1];   // (V,C) float32
    float*       out = (float*)d_out;           // (B,T,C) float32
    int*         pred = (int*)d_ws;             // (B*T) int32 scratch

    dim3 g1(BATCH, TLEN / 64);
    rosa_pred_kernel<<<g1, 256, 0, stream>>>(idx, pred);

    const int nrows = BATCH * TLEN;             // 16384
    rosa_gather_kernel<<<nrows / 4, 256, 0, stream>>>(pred, emb, out);
}

// Round 3
// 200.601 us; speedup vs baseline: 1.1666x; 1.1666x over previous
//
#include <hip/hip_runtime.h>

#define BATCH 8
#define TLEN  2048
#define CDIM  768

// ---------------------------------------------------------------------------
// Fused ROSA predictor + embedding gather.
//
// One wave per output row (b,i):
//   1. block stages x[b,:] (8KB) into LDS via int4 loads
//   2. 64 lanes split j in [0,i) stride-64 (conflict-free LDS, <=32 iters/lane)
//      lazily scoring only j with x[j]==x[i] (only those can win the argmax:
//      any L>=1 score >= 1.0 beats every L==0 score <= 0.0205)
//   3. exact f32 score s = f32(L) + f32(j)*1e-5f (separate rounding, no FMA),
//      argmax with first-occurrence (= smallest j among bitwise-max s)
//   4. wave writes out[b,i,:]: emb[pred,:] or zeros, 3 x float4 per lane
// ---------------------------------------------------------------------------
__global__ __launch_bounds__(256) void rosa_fused_kernel(const int* __restrict__ idx,
                                                         const float* __restrict__ emb,
                                                         float* __restrict__ out) {
    __shared__ int xs[TLEN];
    const int b    = blockIdx.y;
    const int i0   = blockIdx.x * 4;
    const int tid  = threadIdx.x;
    const int wave = tid >> 6;
    const int lane = tid & 63;

    // stage token row (2048 ints = 512 int4, 2 per thread)
    const int4* __restrict__ xr4 = (const int4*)(idx + b * TLEN);
    int4* xs4 = (int4*)xs;
    #pragma unroll
    for (int t = tid; t < TLEN / 4; t += 256) xs4[t] = xr4[t];
    __syncthreads();

    const int i  = i0 + wave;
    const int xi = xs[i];

    float bestS = -1.0f;
    int   bestJ = 0;

    // lanes cover j = lane, lane+64, ... ; ascending within lane, and the
    // reduce prefers smaller j on bitwise-equal s -> global first-max.
    #pragma unroll 4
    for (int j = lane; j < i; j += 64) {
        if (xs[j] == xi) {
            // walk back the diagonal; DP floor is column 0 (m <= j)
            int L = 1;
            int m = 1;
            while (m <= j && xs[i - m] == xs[j - m]) { ++L; ++m; }
            const float s = __fadd_rn((float)L, __fmul_rn((float)j, 1e-5f));
            if (s > bestS) { bestS = s; bestJ = j; }   // strict > == first max
        }
    }

    // 64-lane butterfly reduce: bigger s wins; tie -> smaller j
    #pragma unroll
    for (int off = 32; off >= 1; off >>= 1) {
        const float oS = __shfl_xor(bestS, off, 64);
        const int   oJ = __shfl_xor(bestJ, off, 64);
        if (oS > bestS || (oS == bestS && oJ < bestJ)) { bestS = oS; bestJ = oJ; }
    }

    const int p = (bestS >= 0.5f) ? xs[min(bestJ + 1, TLEN - 1)] : -1;

    // write out[b,i,:]  (768 floats = 3 float4 per lane, coalesced)
    float4* __restrict__ o = (float4*)(out + (size_t)(b * TLEN + i) * CDIM);
    if (p < 0) {
        const float4 z = make_float4(0.f, 0.f, 0.f, 0.f);
        #pragma unroll
        for (int k = 0; k < 3; ++k) o[lane + k * 64] = z;
    } else {
        const float4* __restrict__ e = (const float4*)(emb + (size_t)p * CDIM);
        #pragma unroll
        for (int k = 0; k < 3; ++k) o[lane + k * 64] = e[lane + k * 64];
    }
}

extern "C" void kernel_launch(void* const* d_in, const int* in_sizes, int n_in,
                              void* d_out, int out_size, void* d_ws, size_t ws_size,
                              hipStream_t stream) {
    const int*   idx = (const int*)d_in[0];     // (B,T) int32
    const float* emb = (const float*)d_in[1];   // (V,C) float32
    float*       out = (float*)d_out;           // (B,T,C) float32

    dim3 grid(TLEN / 4, BATCH);                 // one wave per (b,i) row
    rosa_fused_kernel<<<grid, 256, 0, stream>>>(idx, emb, out);
}